// Round 1
// baseline (409.695 us; speedup 1.0000x reference)
//
#include <hip/hip_runtime.h>
#include <hip/hip_bf16.h>

// GraphSAGE 2-layer + classifier on MI355X.
// Strategy: build CSR (deg count + scan + scatter) once per call, aggregate
// with one wave per node (f32 accumulate, bf16 out), run layer GEMMs as
// K=512 dual-input bf16 MFMA GEMMs (16x16x32), classifier as vector kernel.
// Workspace use: ~45 MB.

#define FEAT 256
#define NCLS 16

typedef __bf16 bf16x8 __attribute__((ext_vector_type(8)));
typedef __bf16 bf16x4 __attribute__((ext_vector_type(4)));
typedef float  f32x4  __attribute__((ext_vector_type(4)));

// ---------------- CSR build ----------------

__global__ void count_deg_kernel(const int* __restrict__ dst, int* __restrict__ deg, int E) {
    int e = blockIdx.x * blockDim.x + threadIdx.x;
    if (e < E) atomicAdd(&deg[dst[e]], 1);
}

__global__ void scan_kernel(const int* __restrict__ deg, int* __restrict__ row_ptr,
                            int* __restrict__ fill_pos, int n) {
    __shared__ int part[1024];
    int t = threadIdx.x;
    const int chunk = (n + 1023) / 1024;
    int base = t * chunk;
    int s = 0;
    for (int i = 0; i < chunk; ++i) { int idx = base + i; if (idx < n) s += deg[idx]; }
    part[t] = s;
    __syncthreads();
    for (int off = 1; off < 1024; off <<= 1) {
        int v = (t >= off) ? part[t - off] : 0;
        __syncthreads();
        part[t] += v;
        __syncthreads();
    }
    int run = (t == 0) ? 0 : part[t - 1];
    for (int i = 0; i < chunk; ++i) {
        int idx = base + i;
        if (idx < n) { row_ptr[idx] = run; fill_pos[idx] = run; run += deg[idx]; }
    }
    if (t == 1023) row_ptr[n] = run;   // == E
}

__global__ void fill_kernel(const int* __restrict__ src, const int* __restrict__ dst,
                            int* __restrict__ fill_pos, int* __restrict__ csr, int E) {
    int e = blockIdx.x * blockDim.x + threadIdx.x;
    if (e < E) {
        int d = dst[e];
        int p = atomicAdd(&fill_pos[d], 1);
        csr[p] = src[e];
    }
}

// ---------------- dtype prep ----------------

// WT[n][k] = W[k][n], bf16. Makes MFMA B-fragment loads 16B-contiguous.
__global__ void wtrans_kernel(const float* __restrict__ W, __bf16* __restrict__ WT) {
    int n = blockIdx.x, k = threadIdx.x;
    WT[n * FEAT + k] = (__bf16)W[k * FEAT + n];
}

__global__ void cvt_kernel(const float* __restrict__ x, __bf16* __restrict__ xb, int n4) {
    int i = blockIdx.x * blockDim.x + threadIdx.x;
    if (i < n4) {
        f32x4 v = ((const f32x4*)x)[i];
        bf16x4 o;
        #pragma unroll
        for (int j = 0; j < 4; ++j) o[j] = (__bf16)v[j];
        ((bf16x4*)xb)[i] = o;
    }
}

// ---------------- mean aggregation (one wave per node) ----------------

__global__ void agg_f32_kernel(const float* __restrict__ x, const int* __restrict__ row_ptr,
                               const int* __restrict__ csr, __bf16* __restrict__ out, int n) {
    int node = blockIdx.x * 4 + (threadIdx.x >> 6);
    if (node >= n) return;
    int lane = threadIdx.x & 63;
    int beg = row_ptr[node], end = row_ptr[node + 1];
    f32x4 s = {0.f, 0.f, 0.f, 0.f};
    int e = beg;
    for (; e + 1 < end; e += 2) {
        int j0 = csr[e], j1 = csr[e + 1];
        f32x4 v0 = ((const f32x4*)(x + (size_t)j0 * FEAT))[lane];
        f32x4 v1 = ((const f32x4*)(x + (size_t)j1 * FEAT))[lane];
        s += v0;
        s += v1;
    }
    if (e < end) {
        int j = csr[e];
        s += ((const f32x4*)(x + (size_t)j * FEAT))[lane];
    }
    float inv = (end > beg) ? 1.0f / (float)(end - beg) : 0.0f;
    bf16x4 o;
    #pragma unroll
    for (int j = 0; j < 4; ++j) o[j] = (__bf16)(s[j] * inv);
    ((bf16x4*)(out + (size_t)node * FEAT))[lane] = o;
}

__global__ void agg_bf16_kernel(const __bf16* __restrict__ h, const int* __restrict__ row_ptr,
                                const int* __restrict__ csr, __bf16* __restrict__ out, int n) {
    int node = blockIdx.x * 4 + (threadIdx.x >> 6);
    if (node >= n) return;
    int lane = threadIdx.x & 63;
    int beg = row_ptr[node], end = row_ptr[node + 1];
    f32x4 s = {0.f, 0.f, 0.f, 0.f};
    int e = beg;
    for (; e + 1 < end; e += 2) {
        int j0 = csr[e], j1 = csr[e + 1];
        bf16x4 v0 = ((const bf16x4*)(h + (size_t)j0 * FEAT))[lane];
        bf16x4 v1 = ((const bf16x4*)(h + (size_t)j1 * FEAT))[lane];
        #pragma unroll
        for (int j = 0; j < 4; ++j) s[j] += (float)v0[j] + (float)v1[j];
    }
    if (e < end) {
        int jj = csr[e];
        bf16x4 v = ((const bf16x4*)(h + (size_t)jj * FEAT))[lane];
        #pragma unroll
        for (int j = 0; j < 4; ++j) s[j] += (float)v[j];
    }
    float inv = (end > beg) ? 1.0f / (float)(end - beg) : 0.0f;
    bf16x4 o;
    #pragma unroll
    for (int j = 0; j < 4; ++j) o[j] = (__bf16)(s[j] * inv);
    ((bf16x4*)(out + (size_t)node * FEAT))[lane] = o;
}

// ---------------- dual-input MFMA GEMM: out = act(A1@B1 + A2@B2 + bias) ----------------
// A1,A2: [M,256] bf16 row-major. B1T,B2T: [256,256] bf16, n-major (W transposed).
// Block: 256 thr (4 waves). Block tile 64 x 256; wave handles 64 x 64 via 4x4
// 16x16 MFMA fragments. K=256 per input, looped over both inputs (K=512 total).
// MFMA layouts (HW-verified m89/m91): A: row=lane&15, k=quad*8+j;
// B: col=lane&15, k=quad*8+j; C/D: col=lane&15, row=quad*4+reg.

template<int DO_RELU>
__global__ __launch_bounds__(256) void gemm_dual_kernel(
    const __bf16* __restrict__ A1, const __bf16* __restrict__ A2,
    const __bf16* __restrict__ B1T, const __bf16* __restrict__ B2T,
    const float* __restrict__ bias, __bf16* __restrict__ out, int M)
{
    int m0   = blockIdx.x * 64;
    int lane = threadIdx.x & 63;
    int wave = threadIdx.x >> 6;
    int l16  = lane & 15, quad = lane >> 4;

    f32x4 acc[4][4];
    #pragma unroll
    for (int a = 0; a < 4; ++a)
        #pragma unroll
        for (int b = 0; b < 4; ++b) acc[a][b] = (f32x4){0.f, 0.f, 0.f, 0.f};

    int arow[4];
    #pragma unroll
    for (int mt = 0; mt < 4; ++mt) {
        int r = m0 + mt * 16 + l16;
        arow[mt] = (r < M) ? r : (M - 1);   // clamped read; store is masked
    }
    int nbase = wave * 64;

    for (int pass = 0; pass < 2; ++pass) {
        const __bf16* A  = pass ? A2 : A1;
        const __bf16* BT = pass ? B2T : B1T;
        #pragma unroll 2
        for (int kk = 0; kk < 8; ++kk) {
            int k0 = kk * 32 + quad * 8;
            bf16x8 af[4], bfm[4];
            #pragma unroll
            for (int mt = 0; mt < 4; ++mt)
                af[mt] = *(const bf16x8*)(A + (size_t)arow[mt] * FEAT + k0);
            #pragma unroll
            for (int nt = 0; nt < 4; ++nt)
                bfm[nt] = *(const bf16x8*)(BT + (size_t)(nbase + nt * 16 + l16) * FEAT + k0);
            #pragma unroll
            for (int mt = 0; mt < 4; ++mt)
                #pragma unroll
                for (int nt = 0; nt < 4; ++nt)
                    acc[mt][nt] = __builtin_amdgcn_mfma_f32_16x16x32_bf16(
                        af[mt], bfm[nt], acc[mt][nt], 0, 0, 0);
        }
    }

    #pragma unroll
    for (int nt = 0; nt < 4; ++nt) {
        int col = nbase + nt * 16 + l16;
        float bv = bias[col];
        #pragma unroll
        for (int mt = 0; mt < 4; ++mt) {
            #pragma unroll
            for (int r = 0; r < 4; ++r) {
                int row = m0 + mt * 16 + quad * 4 + r;
                if (row < M) {
                    float v = acc[mt][nt][r] + bv;
                    if (DO_RELU) v = v > 0.f ? v : 0.f;
                    out[(size_t)row * FEAT + col] = (__bf16)v;
                }
            }
        }
    }
}

// ---------------- classifier: out[M,16] = z[M,256] @ Wc[256,16] + bc ----------------

__global__ void cls_kernel(const __bf16* __restrict__ z, const float* __restrict__ Wc,
                           const float* __restrict__ bc, float* __restrict__ out, int M) {
    __shared__ float wcs[FEAT * NCLS];   // 16 KB
    for (int i = threadIdx.x; i < FEAT * NCLS; i += blockDim.x) wcs[i] = Wc[i];
    __syncthreads();

    int t = blockIdx.x * blockDim.x + threadIdx.x;
    int row = t >> 4, c = t & 15;
    if (row >= M) return;
    const __bf16* zr = z + (size_t)row * FEAT;
    float s = 0.f;
    for (int k = 0; k < FEAT; k += 8) {
        bf16x8 zv = *(const bf16x8*)(zr + k);
        #pragma unroll
        for (int j = 0; j < 8; ++j) s += (float)zv[j] * wcs[(k + j) * NCLS + c];
    }
    out[t] = s + bc[c];
}

// ---------------- launch ----------------

extern "C" void kernel_launch(void* const* d_in, const int* in_sizes, int n_in,
                              void* d_out, int out_size, void* d_ws, size_t ws_size,
                              hipStream_t stream) {
    const float* x   = (const float*)d_in[0];
    const int*   ei  = (const int*)d_in[1];
    const float* W1l = (const float*)d_in[2];
    const float* b1  = (const float*)d_in[3];
    const float* W1r = (const float*)d_in[4];
    const float* W2l = (const float*)d_in[5];
    const float* b2  = (const float*)d_in[6];
    const float* W2r = (const float*)d_in[7];
    const float* Wc  = (const float*)d_in[8];
    const float* bc  = (const float*)d_in[9];
    float* out = (float*)d_out;

    const int n = in_sizes[0] / FEAT;   // 20000
    const int E = in_sizes[1] / 2;      // 640000
    const int* srcp = ei;
    const int* dstp = ei + E;

    char* p = (char*)d_ws;
    auto alloc = [&](size_t bytes) { char* r = p; p += (bytes + 511) & ~511ull; return r; };
    int* deg       = (int*)alloc((size_t)n * 4);
    int* row_ptr   = (int*)alloc((size_t)(n + 1) * 4);
    int* fill_pos  = (int*)alloc((size_t)n * 4);
    int* csr       = (int*)alloc((size_t)E * 4);
    __bf16* W1lT   = (__bf16*)alloc((size_t)FEAT * FEAT * 2);
    __bf16* W1rT   = (__bf16*)alloc((size_t)FEAT * FEAT * 2);
    __bf16* W2lT   = (__bf16*)alloc((size_t)FEAT * FEAT * 2);
    __bf16* W2rT   = (__bf16*)alloc((size_t)FEAT * FEAT * 2);
    __bf16* xb     = (__bf16*)alloc((size_t)n * FEAT * 2);
    __bf16* aggb   = (__bf16*)alloc((size_t)n * FEAT * 2);
    __bf16* hb     = (__bf16*)alloc((size_t)n * FEAT * 2);
    __bf16* zb     = (__bf16*)alloc((size_t)n * FEAT * 2);

    // CSR build
    hipMemsetAsync(deg, 0, (size_t)n * 4, stream);
    count_deg_kernel<<<(E + 255) / 256, 256, 0, stream>>>(dstp, deg, E);
    scan_kernel<<<1, 1024, 0, stream>>>(deg, row_ptr, fill_pos, n);
    fill_kernel<<<(E + 255) / 256, 256, 0, stream>>>(srcp, dstp, fill_pos, csr, E);

    // dtype prep
    wtrans_kernel<<<FEAT, FEAT, 0, stream>>>(W1l, W1lT);
    wtrans_kernel<<<FEAT, FEAT, 0, stream>>>(W1r, W1rT);
    wtrans_kernel<<<FEAT, FEAT, 0, stream>>>(W2l, W2lT);
    wtrans_kernel<<<FEAT, FEAT, 0, stream>>>(W2r, W2rT);
    int n4 = n * FEAT / 4;
    cvt_kernel<<<(n4 + 255) / 256, 256, 0, stream>>>(x, xb, n4);

    // layer 1
    agg_f32_kernel<<<(n + 3) / 4, 256, 0, stream>>>(x, row_ptr, csr, aggb, n);
    gemm_dual_kernel<1><<<(n + 63) / 64, 256, 0, stream>>>(aggb, xb, W1lT, W1rT, b1, hb, n);

    // layer 2
    agg_bf16_kernel<<<(n + 3) / 4, 256, 0, stream>>>(hb, row_ptr, csr, aggb, n);
    gemm_dual_kernel<0><<<(n + 63) / 64, 256, 0, stream>>>(aggb, hb, W2lT, W2rT, b2, zb, n);

    // classifier
    cls_kernel<<<(n * NCLS + 255) / 256, 256, 0, stream>>>(zb, Wc, bc, out, n);
}

// Round 2
// 363.535 us; speedup vs baseline: 1.1270x; 1.1270x over previous
//
#include <hip/hip_runtime.h>
#include <hip/hip_bf16.h>

// GraphSAGE 2-layer + classifier on MI355X.
// R2: all gathers in bf16 (halves layer-1 agg traffic), GEMM 32-row tiles
// (625 blocks, better occupancy/tail), classifier via MFMA (kills 16x z
// re-read). CSR build unchanged.

#define FEAT 256
#define NCLS 16

typedef __bf16 bf16x8 __attribute__((ext_vector_type(8)));
typedef __bf16 bf16x4 __attribute__((ext_vector_type(4)));
typedef float  f32x4  __attribute__((ext_vector_type(4)));

// ---------------- CSR build ----------------

__global__ void count_deg_kernel(const int* __restrict__ dst, int* __restrict__ deg, int E) {
    int e = blockIdx.x * blockDim.x + threadIdx.x;
    if (e < E) atomicAdd(&deg[dst[e]], 1);
}

__global__ void scan_kernel(const int* __restrict__ deg, int* __restrict__ row_ptr,
                            int* __restrict__ fill_pos, int n) {
    __shared__ int part[1024];
    int t = threadIdx.x;
    const int chunk = (n + 1023) / 1024;
    int base = t * chunk;
    int s = 0;
    for (int i = 0; i < chunk; ++i) { int idx = base + i; if (idx < n) s += deg[idx]; }
    part[t] = s;
    __syncthreads();
    for (int off = 1; off < 1024; off <<= 1) {
        int v = (t >= off) ? part[t - off] : 0;
        __syncthreads();
        part[t] += v;
        __syncthreads();
    }
    int run = (t == 0) ? 0 : part[t - 1];
    for (int i = 0; i < chunk; ++i) {
        int idx = base + i;
        if (idx < n) { row_ptr[idx] = run; fill_pos[idx] = run; run += deg[idx]; }
    }
    if (t == 1023) row_ptr[n] = run;   // == E
}

__global__ void fill_kernel(const int* __restrict__ src, const int* __restrict__ dst,
                            int* __restrict__ fill_pos, int* __restrict__ csr, int E) {
    int e = blockIdx.x * blockDim.x + threadIdx.x;
    if (e < E) {
        int d = dst[e];
        int p = atomicAdd(&fill_pos[d], 1);
        csr[p] = src[e];
    }
}

// ---------------- dtype prep ----------------

// WT[n][k] = W[k][n], bf16 (256x256 weights).
__global__ void wtrans_kernel(const float* __restrict__ W, __bf16* __restrict__ WT) {
    int n = blockIdx.x, k = threadIdx.x;
    WT[n * FEAT + k] = (__bf16)W[k * FEAT + n];
}

// WcT[c][k] = Wc[k][c], bf16 (256x16 classifier weight).
__global__ void wtransC_kernel(const float* __restrict__ Wc, __bf16* __restrict__ WcT) {
    int c = blockIdx.x, k = threadIdx.x;
    WcT[c * FEAT + k] = (__bf16)Wc[k * NCLS + c];
}

__global__ void cvt_kernel(const float* __restrict__ x, __bf16* __restrict__ xb, int n4) {
    int i = blockIdx.x * blockDim.x + threadIdx.x;
    if (i < n4) {
        f32x4 v = ((const f32x4*)x)[i];
        bf16x4 o;
        #pragma unroll
        for (int j = 0; j < 4; ++j) o[j] = (__bf16)v[j];
        ((bf16x4*)xb)[i] = o;
    }
}

// ---------------- mean aggregation (one wave per node, bf16 in/out, f32 acc) ----------------

__global__ void agg_bf16_kernel(const __bf16* __restrict__ h, const int* __restrict__ row_ptr,
                                const int* __restrict__ csr, __bf16* __restrict__ out, int n) {
    int node = blockIdx.x * 4 + (threadIdx.x >> 6);
    if (node >= n) return;
    int lane = threadIdx.x & 63;
    int beg = row_ptr[node], end = row_ptr[node + 1];
    f32x4 s = {0.f, 0.f, 0.f, 0.f};
    int e = beg;
    for (; e + 3 < end; e += 4) {
        int j0 = csr[e], j1 = csr[e + 1], j2 = csr[e + 2], j3 = csr[e + 3];
        bf16x4 v0 = ((const bf16x4*)(h + (size_t)j0 * FEAT))[lane];
        bf16x4 v1 = ((const bf16x4*)(h + (size_t)j1 * FEAT))[lane];
        bf16x4 v2 = ((const bf16x4*)(h + (size_t)j2 * FEAT))[lane];
        bf16x4 v3 = ((const bf16x4*)(h + (size_t)j3 * FEAT))[lane];
        #pragma unroll
        for (int j = 0; j < 4; ++j)
            s[j] += ((float)v0[j] + (float)v1[j]) + ((float)v2[j] + (float)v3[j]);
    }
    for (; e < end; ++e) {
        int jj = csr[e];
        bf16x4 v = ((const bf16x4*)(h + (size_t)jj * FEAT))[lane];
        #pragma unroll
        for (int j = 0; j < 4; ++j) s[j] += (float)v[j];
    }
    float inv = (end > beg) ? 1.0f / (float)(end - beg) : 0.0f;
    bf16x4 o;
    #pragma unroll
    for (int j = 0; j < 4; ++j) o[j] = (__bf16)(s[j] * inv);
    ((bf16x4*)(out + (size_t)node * FEAT))[lane] = o;
}

// ---------------- dual-input MFMA GEMM: out = act(A1@B1 + A2@B2 + bias) ----------------
// A1,A2: [M,256] bf16 row-major. B1T,B2T: [256,256] bf16 n-major.
// Block: 256 thr (4 waves), tile 32 x 256; wave = 32 rows x 64 cols via 2x4
// 16x16x32 fragments. grid = ceil(M/32) = 625 blocks (~2.4/CU).
// Layouts (HW-verified m89/m91): A: row=lane&15, k=quad*8+j;
// B: col=lane&15, k=quad*8+j; C/D: col=lane&15, row=quad*4+reg.

template<int DO_RELU>
__global__ __launch_bounds__(256) void gemm_dual_kernel(
    const __bf16* __restrict__ A1, const __bf16* __restrict__ A2,
    const __bf16* __restrict__ B1T, const __bf16* __restrict__ B2T,
    const float* __restrict__ bias, __bf16* __restrict__ out, int M)
{
    int m0   = blockIdx.x * 32;
    int lane = threadIdx.x & 63;
    int wave = threadIdx.x >> 6;
    int l16  = lane & 15, quad = lane >> 4;

    f32x4 acc[2][4];
    #pragma unroll
    for (int a = 0; a < 2; ++a)
        #pragma unroll
        for (int b = 0; b < 4; ++b) acc[a][b] = (f32x4){0.f, 0.f, 0.f, 0.f};

    int arow[2];
    #pragma unroll
    for (int mt = 0; mt < 2; ++mt) {
        int r = m0 + mt * 16 + l16;
        arow[mt] = (r < M) ? r : (M - 1);   // clamped read; store is masked
    }
    int nbase = wave * 64;

    for (int pass = 0; pass < 2; ++pass) {
        const __bf16* A  = pass ? A2 : A1;
        const __bf16* BT = pass ? B2T : B1T;
        #pragma unroll 2
        for (int kk = 0; kk < 8; ++kk) {
            int k0 = kk * 32 + quad * 8;
            bf16x8 af[2], bfm[4];
            #pragma unroll
            for (int mt = 0; mt < 2; ++mt)
                af[mt] = *(const bf16x8*)(A + (size_t)arow[mt] * FEAT + k0);
            #pragma unroll
            for (int nt = 0; nt < 4; ++nt)
                bfm[nt] = *(const bf16x8*)(BT + (size_t)(nbase + nt * 16 + l16) * FEAT + k0);
            #pragma unroll
            for (int mt = 0; mt < 2; ++mt)
                #pragma unroll
                for (int nt = 0; nt < 4; ++nt)
                    acc[mt][nt] = __builtin_amdgcn_mfma_f32_16x16x32_bf16(
                        af[mt], bfm[nt], acc[mt][nt], 0, 0, 0);
        }
    }

    #pragma unroll
    for (int nt = 0; nt < 4; ++nt) {
        int col = nbase + nt * 16 + l16;
        float bv = bias[col];
        #pragma unroll
        for (int mt = 0; mt < 2; ++mt) {
            #pragma unroll
            for (int r = 0; r < 4; ++r) {
                int row = m0 + mt * 16 + quad * 4 + r;
                if (row < M) {
                    float v = acc[mt][nt][r] + bv;
                    if (DO_RELU) v = v > 0.f ? v : 0.f;
                    out[(size_t)row * FEAT + col] = (__bf16)v;
                }
            }
        }
    }
}

// ---------------- classifier via MFMA: out[M,16] = z[M,256] @ Wc[256,16] + bc ----------------
// One wave per 16 rows; NCLS=16 fills the 16-col MFMA tile exactly.

__global__ __launch_bounds__(256) void cls_kernel(
    const __bf16* __restrict__ z, const __bf16* __restrict__ WcT,
    const float* __restrict__ bc, float* __restrict__ out, int M)
{
    int lane = threadIdx.x & 63, wave = threadIdx.x >> 6;
    int l16 = lane & 15, quad = lane >> 4;
    int m0 = blockIdx.x * 64 + wave * 16;
    int arow = m0 + l16;
    if (arow >= M) arow = M - 1;

    f32x4 acc = {0.f, 0.f, 0.f, 0.f};
    #pragma unroll
    for (int kk = 0; kk < 8; ++kk) {
        int k0 = kk * 32 + quad * 8;
        bf16x8 a = *(const bf16x8*)(z + (size_t)arow * FEAT + k0);
        bf16x8 b = *(const bf16x8*)(WcT + (size_t)l16 * FEAT + k0);
        acc = __builtin_amdgcn_mfma_f32_16x16x32_bf16(a, b, acc, 0, 0, 0);
    }
    float bv = bc[l16];
    #pragma unroll
    for (int r = 0; r < 4; ++r) {
        int row = m0 + quad * 4 + r;
        if (row < M) out[(size_t)row * NCLS + l16] = acc[r] + bv;
    }
}

// ---------------- launch ----------------

extern "C" void kernel_launch(void* const* d_in, const int* in_sizes, int n_in,
                              void* d_out, int out_size, void* d_ws, size_t ws_size,
                              hipStream_t stream) {
    const float* x   = (const float*)d_in[0];
    const int*   ei  = (const int*)d_in[1];
    const float* W1l = (const float*)d_in[2];
    const float* b1  = (const float*)d_in[3];
    const float* W1r = (const float*)d_in[4];
    const float* W2l = (const float*)d_in[5];
    const float* b2  = (const float*)d_in[6];
    const float* W2r = (const float*)d_in[7];
    const float* Wc  = (const float*)d_in[8];
    const float* bc  = (const float*)d_in[9];
    float* out = (float*)d_out;

    const int n = in_sizes[0] / FEAT;   // 20000
    const int E = in_sizes[1] / 2;      // 640000
    const int* srcp = ei;
    const int* dstp = ei + E;

    char* p = (char*)d_ws;
    auto alloc = [&](size_t bytes) { char* r = p; p += (bytes + 511) & ~511ull; return r; };
    int* deg       = (int*)alloc((size_t)n * 4);
    int* row_ptr   = (int*)alloc((size_t)(n + 1) * 4);
    int* fill_pos  = (int*)alloc((size_t)n * 4);
    int* csr       = (int*)alloc((size_t)E * 4);
    __bf16* W1lT   = (__bf16*)alloc((size_t)FEAT * FEAT * 2);
    __bf16* W1rT   = (__bf16*)alloc((size_t)FEAT * FEAT * 2);
    __bf16* W2lT   = (__bf16*)alloc((size_t)FEAT * FEAT * 2);
    __bf16* W2rT   = (__bf16*)alloc((size_t)FEAT * FEAT * 2);
    __bf16* WcT    = (__bf16*)alloc((size_t)NCLS * FEAT * 2);
    __bf16* xb     = (__bf16*)alloc((size_t)n * FEAT * 2);
    __bf16* aggb   = (__bf16*)alloc((size_t)n * FEAT * 2);
    __bf16* hb     = (__bf16*)alloc((size_t)n * FEAT * 2);
    __bf16* zb     = (__bf16*)alloc((size_t)n * FEAT * 2);

    // CSR build
    hipMemsetAsync(deg, 0, (size_t)n * 4, stream);
    count_deg_kernel<<<(E + 255) / 256, 256, 0, stream>>>(dstp, deg, E);
    scan_kernel<<<1, 1024, 0, stream>>>(deg, row_ptr, fill_pos, n);
    fill_kernel<<<(E + 255) / 256, 256, 0, stream>>>(srcp, dstp, fill_pos, csr, E);

    // dtype prep
    wtrans_kernel<<<FEAT, FEAT, 0, stream>>>(W1l, W1lT);
    wtrans_kernel<<<FEAT, FEAT, 0, stream>>>(W1r, W1rT);
    wtrans_kernel<<<FEAT, FEAT, 0, stream>>>(W2l, W2lT);
    wtrans_kernel<<<FEAT, FEAT, 0, stream>>>(W2r, W2rT);
    wtransC_kernel<<<NCLS, FEAT, 0, stream>>>(Wc, WcT);
    int n4 = n * FEAT / 4;
    cvt_kernel<<<(n4 + 255) / 256, 256, 0, stream>>>(x, xb, n4);

    // layer 1 (aggregate from bf16 xb)
    agg_bf16_kernel<<<(n + 3) / 4, 256, 0, stream>>>(xb, row_ptr, csr, aggb, n);
    gemm_dual_kernel<1><<<(n + 31) / 32, 256, 0, stream>>>(aggb, xb, W1lT, W1rT, b1, hb, n);

    // layer 2
    agg_bf16_kernel<<<(n + 3) / 4, 256, 0, stream>>>(hb, row_ptr, csr, aggb, n);
    gemm_dual_kernel<0><<<(n + 31) / 32, 256, 0, stream>>>(aggb, hb, W2lT, W2rT, b2, zb, n);

    // classifier
    cls_kernel<<<(n + 63) / 64, 256, 0, stream>>>(zb, WcT, bc, out, n);
}

// Round 3
// 336.351 us; speedup vs baseline: 1.2181x; 1.0808x over previous
//
#include <hip/hip_runtime.h>
#include <hip/hip_bf16.h>

// GraphSAGE 2-layer + classifier on MI355X.
// R3: (a) layer-1 aggregation gathers fp8-e4m3 (256B/row, 5MB table ~ L2-resident);
//     (b) classifier fused into gemm-2 epilogue via LDS (no zb round-trip);
//     (c) weight prep consolidated to 1 kernel, cvt emits bf16+fp8 in one pass.
// Layer-2 aggregation stays bf16 (error-budget calibration round for fp8).

#define FEAT 256
#define NCLS 16

typedef __bf16 bf16x8 __attribute__((ext_vector_type(8)));
typedef __bf16 bf16x4 __attribute__((ext_vector_type(4)));
typedef float  f32x4  __attribute__((ext_vector_type(4)));
typedef float  f32x2  __attribute__((ext_vector_type(2)));

// ---------------- CSR build ----------------

__global__ void count_deg_kernel(const int* __restrict__ dst, int* __restrict__ deg, int E) {
    int e = blockIdx.x * blockDim.x + threadIdx.x;
    if (e < E) atomicAdd(&deg[dst[e]], 1);
}

__global__ void scan_kernel(const int* __restrict__ deg, int* __restrict__ row_ptr,
                            int* __restrict__ fill_pos, int n) {
    __shared__ int part[1024];
    int t = threadIdx.x;
    const int chunk = (n + 1023) / 1024;
    int base = t * chunk;
    int s = 0;
    for (int i = 0; i < chunk; ++i) { int idx = base + i; if (idx < n) s += deg[idx]; }
    part[t] = s;
    __syncthreads();
    for (int off = 1; off < 1024; off <<= 1) {
        int v = (t >= off) ? part[t - off] : 0;
        __syncthreads();
        part[t] += v;
        __syncthreads();
    }
    int run = (t == 0) ? 0 : part[t - 1];
    for (int i = 0; i < chunk; ++i) {
        int idx = base + i;
        if (idx < n) { row_ptr[idx] = run; fill_pos[idx] = run; run += deg[idx]; }
    }
    if (t == 1023) row_ptr[n] = run;   // == E
}

__global__ void fill_kernel(const int* __restrict__ src, const int* __restrict__ dst,
                            int* __restrict__ fill_pos, int* __restrict__ csr, int E) {
    int e = blockIdx.x * blockDim.x + threadIdx.x;
    if (e < E) {
        int d = dst[e];
        int p = atomicAdd(&fill_pos[d], 1);
        csr[p] = src[e];
    }
}

// ---------------- prep: all weight transposes in one launch ----------------
// grid (256, 5): y<4 -> WT[n][k] = W[k][n] for the four 256x256 weights;
// y==4 -> WcT[c][k] = Wc[k][c] (first 16 blocks only).

__global__ void prep_w_kernel(const float* __restrict__ W1l, const float* __restrict__ W1r,
                              const float* __restrict__ W2l, const float* __restrict__ W2r,
                              const float* __restrict__ Wc,
                              __bf16* __restrict__ W1lT, __bf16* __restrict__ W1rT,
                              __bf16* __restrict__ W2lT, __bf16* __restrict__ W2rT,
                              __bf16* __restrict__ WcT) {
    int y = blockIdx.y;
    int k = threadIdx.x;
    if (y < 4) {
        const float* W = (y == 0) ? W1l : (y == 1) ? W1r : (y == 2) ? W2l : W2r;
        __bf16* WT = (y == 0) ? W1lT : (y == 1) ? W1rT : (y == 2) ? W2lT : W2rT;
        int nn = blockIdx.x;
        WT[nn * FEAT + k] = (__bf16)W[k * FEAT + nn];
    } else if (blockIdx.x < NCLS) {
        int c = blockIdx.x;
        WcT[c * FEAT + k] = (__bf16)Wc[k * NCLS + c];
    }
}

// x (f32) -> xb (bf16, for GEMM A2) and x8 (fp8 e4m3, for layer-1 gather)

__global__ void cvt_kernel(const float* __restrict__ x, __bf16* __restrict__ xb,
                           unsigned char* __restrict__ x8, int n4) {
    int i = blockIdx.x * blockDim.x + threadIdx.x;
    if (i < n4) {
        f32x4 v = ((const f32x4*)x)[i];
        bf16x4 o;
        #pragma unroll
        for (int j = 0; j < 4; ++j) o[j] = (__bf16)v[j];
        ((bf16x4*)xb)[i] = o;
        int pk = 0;
        pk = __builtin_amdgcn_cvt_pk_fp8_f32(v[0], v[1], pk, false);
        pk = __builtin_amdgcn_cvt_pk_fp8_f32(v[2], v[3], pk, true);
        ((int*)x8)[i] = pk;
    }
}

// ---------------- mean aggregation ----------------
// fp8 variant (layer 1): row = 256 bytes, lane reads 1 uint (4 feats).

__global__ void agg_fp8_kernel(const unsigned char* __restrict__ x8, const int* __restrict__ row_ptr,
                               const int* __restrict__ csr, __bf16* __restrict__ out, int n) {
    int node = blockIdx.x * 4 + (threadIdx.x >> 6);
    if (node >= n) return;
    int lane = threadIdx.x & 63;
    int beg = row_ptr[node], end = row_ptr[node + 1];
    f32x4 s = {0.f, 0.f, 0.f, 0.f};
    int e = beg;
    for (; e + 3 < end; e += 4) {
        int j0 = csr[e], j1 = csr[e + 1], j2 = csr[e + 2], j3 = csr[e + 3];
        unsigned int u0 = ((const unsigned int*)(x8 + (size_t)j0 * FEAT))[lane];
        unsigned int u1 = ((const unsigned int*)(x8 + (size_t)j1 * FEAT))[lane];
        unsigned int u2 = ((const unsigned int*)(x8 + (size_t)j2 * FEAT))[lane];
        unsigned int u3 = ((const unsigned int*)(x8 + (size_t)j3 * FEAT))[lane];
        #pragma unroll
        for (int q = 0; q < 4; ++q) {
            unsigned int u = (q == 0) ? u0 : (q == 1) ? u1 : (q == 2) ? u2 : u3;
            f32x2 lo = __builtin_amdgcn_cvt_pk_f32_fp8(u, false);
            f32x2 hi = __builtin_amdgcn_cvt_pk_f32_fp8(u, true);
            s[0] += lo[0]; s[1] += lo[1]; s[2] += hi[0]; s[3] += hi[1];
        }
    }
    for (; e < end; ++e) {
        unsigned int u = ((const unsigned int*)(x8 + (size_t)csr[e] * FEAT))[lane];
        f32x2 lo = __builtin_amdgcn_cvt_pk_f32_fp8(u, false);
        f32x2 hi = __builtin_amdgcn_cvt_pk_f32_fp8(u, true);
        s[0] += lo[0]; s[1] += lo[1]; s[2] += hi[0]; s[3] += hi[1];
    }
    float inv = (end > beg) ? 1.0f / (float)(end - beg) : 0.0f;
    bf16x4 o;
    #pragma unroll
    for (int j = 0; j < 4; ++j) o[j] = (__bf16)(s[j] * inv);
    ((bf16x4*)(out + (size_t)node * FEAT))[lane] = o;
}

// bf16 variant (layer 2): lane reads bf16x4 (8 bytes) per row.

__global__ void agg_bf16_kernel(const __bf16* __restrict__ h, const int* __restrict__ row_ptr,
                                const int* __restrict__ csr, __bf16* __restrict__ out, int n) {
    int node = blockIdx.x * 4 + (threadIdx.x >> 6);
    if (node >= n) return;
    int lane = threadIdx.x & 63;
    int beg = row_ptr[node], end = row_ptr[node + 1];
    f32x4 s = {0.f, 0.f, 0.f, 0.f};
    int e = beg;
    for (; e + 3 < end; e += 4) {
        int j0 = csr[e], j1 = csr[e + 1], j2 = csr[e + 2], j3 = csr[e + 3];
        bf16x4 v0 = ((const bf16x4*)(h + (size_t)j0 * FEAT))[lane];
        bf16x4 v1 = ((const bf16x4*)(h + (size_t)j1 * FEAT))[lane];
        bf16x4 v2 = ((const bf16x4*)(h + (size_t)j2 * FEAT))[lane];
        bf16x4 v3 = ((const bf16x4*)(h + (size_t)j3 * FEAT))[lane];
        #pragma unroll
        for (int j = 0; j < 4; ++j)
            s[j] += ((float)v0[j] + (float)v1[j]) + ((float)v2[j] + (float)v3[j]);
    }
    for (; e < end; ++e) {
        bf16x4 v = ((const bf16x4*)(h + (size_t)csr[e] * FEAT))[lane];
        #pragma unroll
        for (int j = 0; j < 4; ++j) s[j] += (float)v[j];
    }
    float inv = (end > beg) ? 1.0f / (float)(end - beg) : 0.0f;
    bf16x4 o;
    #pragma unroll
    for (int j = 0; j < 4; ++j) o[j] = (__bf16)(s[j] * inv);
    ((bf16x4*)(out + (size_t)node * FEAT))[lane] = o;
}

// ---------------- layer-1 GEMM: h = relu(A1@B1 + A2@B2 + bias), bf16 out ----------------
// Block 256 thr (4 waves), tile 32 x 256; wave = 2x4 16x16x32 fragments.
// Layouts (HW-verified m89/m91): A: row=lane&15, k=quad*8+j;
// B: col=lane&15, k=quad*8+j; C/D: col=lane&15, row=quad*4+reg.

__global__ __launch_bounds__(256) void gemm_dual_relu_kernel(
    const __bf16* __restrict__ A1, const __bf16* __restrict__ A2,
    const __bf16* __restrict__ B1T, const __bf16* __restrict__ B2T,
    const float* __restrict__ bias, __bf16* __restrict__ out, int M)
{
    int m0   = blockIdx.x * 32;
    int lane = threadIdx.x & 63;
    int wave = threadIdx.x >> 6;
    int l16  = lane & 15, quad = lane >> 4;

    f32x4 acc[2][4];
    #pragma unroll
    for (int a = 0; a < 2; ++a)
        #pragma unroll
        for (int b = 0; b < 4; ++b) acc[a][b] = (f32x4){0.f, 0.f, 0.f, 0.f};

    int arow[2];
    #pragma unroll
    for (int mt = 0; mt < 2; ++mt) {
        int r = m0 + mt * 16 + l16;
        arow[mt] = (r < M) ? r : (M - 1);
    }
    int nbase = wave * 64;

    for (int pass = 0; pass < 2; ++pass) {
        const __bf16* A  = pass ? A2 : A1;
        const __bf16* BT = pass ? B2T : B1T;
        #pragma unroll 2
        for (int kk = 0; kk < 8; ++kk) {
            int k0 = kk * 32 + quad * 8;
            bf16x8 af[2], bfm[4];
            #pragma unroll
            for (int mt = 0; mt < 2; ++mt)
                af[mt] = *(const bf16x8*)(A + (size_t)arow[mt] * FEAT + k0);
            #pragma unroll
            for (int nt = 0; nt < 4; ++nt)
                bfm[nt] = *(const bf16x8*)(BT + (size_t)(nbase + nt * 16 + l16) * FEAT + k0);
            #pragma unroll
            for (int mt = 0; mt < 2; ++mt)
                #pragma unroll
                for (int nt = 0; nt < 4; ++nt)
                    acc[mt][nt] = __builtin_amdgcn_mfma_f32_16x16x32_bf16(
                        af[mt], bfm[nt], acc[mt][nt], 0, 0, 0);
        }
    }

    #pragma unroll
    for (int nt = 0; nt < 4; ++nt) {
        int col = nbase + nt * 16 + l16;
        float bv = bias[col];
        #pragma unroll
        for (int mt = 0; mt < 2; ++mt) {
            #pragma unroll
            for (int r = 0; r < 4; ++r) {
                int row = m0 + mt * 16 + quad * 4 + r;
                if (row < M) {
                    float v = acc[mt][nt][r] + bv;
                    v = v > 0.f ? v : 0.f;
                    out[(size_t)row * FEAT + col] = (__bf16)v;
                }
            }
        }
    }
}

// ---------------- layer-2 GEMM + fused classifier ----------------
// z-tile (32x256, + b2) goes to LDS (padded +8 bf16 to spread banks), then
// waves 0/1 run the z @ WcT MFMA (K=256, 16 cols) and write logits f32.

#define ZPAD 264   // 256 + 8

__global__ __launch_bounds__(256) void gemm_dual_cls_kernel(
    const __bf16* __restrict__ A1, const __bf16* __restrict__ A2,
    const __bf16* __restrict__ B1T, const __bf16* __restrict__ B2T,
    const float* __restrict__ bias, const __bf16* __restrict__ WcT,
    const float* __restrict__ bc, float* __restrict__ out, int M)
{
    __shared__ __bf16 zt[32 * ZPAD];   // 16.9 KB

    int m0   = blockIdx.x * 32;
    int lane = threadIdx.x & 63;
    int wave = threadIdx.x >> 6;
    int l16  = lane & 15, quad = lane >> 4;

    f32x4 acc[2][4];
    #pragma unroll
    for (int a = 0; a < 2; ++a)
        #pragma unroll
        for (int b = 0; b < 4; ++b) acc[a][b] = (f32x4){0.f, 0.f, 0.f, 0.f};

    int arow[2];
    #pragma unroll
    for (int mt = 0; mt < 2; ++mt) {
        int r = m0 + mt * 16 + l16;
        arow[mt] = (r < M) ? r : (M - 1);
    }
    int nbase = wave * 64;

    for (int pass = 0; pass < 2; ++pass) {
        const __bf16* A  = pass ? A2 : A1;
        const __bf16* BT = pass ? B2T : B1T;
        #pragma unroll 2
        for (int kk = 0; kk < 8; ++kk) {
            int k0 = kk * 32 + quad * 8;
            bf16x8 af[2], bfm[4];
            #pragma unroll
            for (int mt = 0; mt < 2; ++mt)
                af[mt] = *(const bf16x8*)(A + (size_t)arow[mt] * FEAT + k0);
            #pragma unroll
            for (int nt = 0; nt < 4; ++nt)
                bfm[nt] = *(const bf16x8*)(BT + (size_t)(nbase + nt * 16 + l16) * FEAT + k0);
            #pragma unroll
            for (int mt = 0; mt < 2; ++mt)
                #pragma unroll
                for (int nt = 0; nt < 4; ++nt)
                    acc[mt][nt] = __builtin_amdgcn_mfma_f32_16x16x32_bf16(
                        af[mt], bfm[nt], acc[mt][nt], 0, 0, 0);
        }
    }

    // epilogue: z (+b2) -> LDS
    #pragma unroll
    for (int nt = 0; nt < 4; ++nt) {
        int col = nbase + nt * 16 + l16;
        float bv = bias[col];
        #pragma unroll
        for (int mt = 0; mt < 2; ++mt) {
            int lr = mt * 16 + quad * 4;
            #pragma unroll
            for (int r = 0; r < 4; ++r)
                zt[(lr + r) * ZPAD + col] = (__bf16)(acc[mt][nt][r] + bv);
        }
    }
    __syncthreads();

    // classifier: waves 0/1, 16 rows each; B-frag from WcT (L2-hot)
    if (wave < 2) {
        int lr = wave * 16 + l16;
        f32x4 c = {0.f, 0.f, 0.f, 0.f};
        #pragma unroll
        for (int kk = 0; kk < 8; ++kk) {
            int k0 = kk * 32 + quad * 8;
            bf16x8 a = *(const bf16x8*)(&zt[lr * ZPAD + k0]);
            bf16x8 b = *(const bf16x8*)(WcT + (size_t)l16 * FEAT + k0);
            c = __builtin_amdgcn_mfma_f32_16x16x32_bf16(a, b, c, 0, 0, 0);
        }
        float bv = bc[l16];
        #pragma unroll
        for (int r = 0; r < 4; ++r) {
            int row = m0 + wave * 16 + quad * 4 + r;
            if (row < M) out[(size_t)row * NCLS + l16] = c[r] + bv;
        }
    }
}

// ---------------- launch ----------------

extern "C" void kernel_launch(void* const* d_in, const int* in_sizes, int n_in,
                              void* d_out, int out_size, void* d_ws, size_t ws_size,
                              hipStream_t stream) {
    const float* x   = (const float*)d_in[0];
    const int*   ei  = (const int*)d_in[1];
    const float* W1l = (const float*)d_in[2];
    const float* b1  = (const float*)d_in[3];
    const float* W1r = (const float*)d_in[4];
    const float* W2l = (const float*)d_in[5];
    const float* b2  = (const float*)d_in[6];
    const float* W2r = (const float*)d_in[7];
    const float* Wc  = (const float*)d_in[8];
    const float* bc  = (const float*)d_in[9];
    float* out = (float*)d_out;

    const int n = in_sizes[0] / FEAT;   // 20000
    const int E = in_sizes[1] / 2;      // 640000
    const int* srcp = ei;
    const int* dstp = ei + E;

    char* p = (char*)d_ws;
    auto alloc = [&](size_t bytes) { char* r = p; p += (bytes + 511) & ~511ull; return r; };
    int* deg       = (int*)alloc((size_t)n * 4);
    int* row_ptr   = (int*)alloc((size_t)(n + 1) * 4);
    int* fill_pos  = (int*)alloc((size_t)n * 4);
    int* csr       = (int*)alloc((size_t)E * 4);
    __bf16* W1lT   = (__bf16*)alloc((size_t)FEAT * FEAT * 2);
    __bf16* W1rT   = (__bf16*)alloc((size_t)FEAT * FEAT * 2);
    __bf16* W2lT   = (__bf16*)alloc((size_t)FEAT * FEAT * 2);
    __bf16* W2rT   = (__bf16*)alloc((size_t)FEAT * FEAT * 2);
    __bf16* WcT    = (__bf16*)alloc((size_t)NCLS * FEAT * 2);
    __bf16* xb     = (__bf16*)alloc((size_t)n * FEAT * 2);
    unsigned char* x8 = (unsigned char*)alloc((size_t)n * FEAT);
    __bf16* aggb   = (__bf16*)alloc((size_t)n * FEAT * 2);
    __bf16* hb     = (__bf16*)alloc((size_t)n * FEAT * 2);

    // CSR build
    hipMemsetAsync(deg, 0, (size_t)n * 4, stream);
    count_deg_kernel<<<(E + 255) / 256, 256, 0, stream>>>(dstp, deg, E);
    scan_kernel<<<1, 1024, 0, stream>>>(deg, row_ptr, fill_pos, n);
    fill_kernel<<<(E + 255) / 256, 256, 0, stream>>>(srcp, dstp, fill_pos, csr, E);

    // prep
    prep_w_kernel<<<dim3(FEAT, 5), FEAT, 0, stream>>>(W1l, W1r, W2l, W2r, Wc,
                                                      W1lT, W1rT, W2lT, W2rT, WcT);
    int n4 = n * FEAT / 4;
    cvt_kernel<<<(n4 + 255) / 256, 256, 0, stream>>>(x, xb, x8, n4);

    // layer 1 (fp8 gather)
    agg_fp8_kernel<<<(n + 3) / 4, 256, 0, stream>>>(x8, row_ptr, csr, aggb, n);
    gemm_dual_relu_kernel<<<(n + 31) / 32, 256, 0, stream>>>(aggb, xb, W1lT, W1rT, b1, hb, n);

    // layer 2 (bf16 gather) + fused classifier
    agg_bf16_kernel<<<(n + 3) / 4, 256, 0, stream>>>(hb, row_ptr, csr, aggb, n);
    gemm_dual_cls_kernel<<<(n + 31) / 32, 256, 0, stream>>>(aggb, hb, W2lT, W2rT, b2,
                                                            WcT, bc, out, n);
}

// Round 4
// 318.666 us; speedup vs baseline: 1.2857x; 1.0555x over previous
//
#include <hip/hip_runtime.h>
#include <hip/hip_bf16.h>

// GraphSAGE 2-layer + classifier on MI355X.
// R4: both aggregations gather fp8-e4m3 (5MB tables, ~L2-resident) with a
// 4-rows-per-load-instruction wave layout (16B/lane dwordx4 + shfl_xor
// butterfly merge). gemm-1 epilogue goes through LDS and emits hb (bf16,
// GEMM-2 root path keeps precision) + h8 (fp8 gather table) with vector
// stores. Classifier stays fused in gemm-2 epilogue.

#define FEAT 256
#define NCLS 16
#define ZPAD 264   // 256 + 8 bf16 pad

typedef __bf16 bf16x8 __attribute__((ext_vector_type(8)));
typedef __bf16 bf16x4 __attribute__((ext_vector_type(4)));
typedef float  f32x4  __attribute__((ext_vector_type(4)));
typedef float  f32x2  __attribute__((ext_vector_type(2)));
typedef unsigned int uint4v __attribute__((ext_vector_type(4)));

// ---------------- CSR build ----------------

__global__ void count_deg_kernel(const int* __restrict__ dst, int* __restrict__ deg, int E) {
    int e = blockIdx.x * blockDim.x + threadIdx.x;
    if (e < E) atomicAdd(&deg[dst[e]], 1);
}

__global__ void scan_kernel(const int* __restrict__ deg, int* __restrict__ row_ptr,
                            int* __restrict__ fill_pos, int n) {
    __shared__ int part[1024];
    int t = threadIdx.x;
    const int chunk = (n + 1023) / 1024;
    int base = t * chunk;
    int s = 0;
    for (int i = 0; i < chunk; ++i) { int idx = base + i; if (idx < n) s += deg[idx]; }
    part[t] = s;
    __syncthreads();
    for (int off = 1; off < 1024; off <<= 1) {
        int v = (t >= off) ? part[t - off] : 0;
        __syncthreads();
        part[t] += v;
        __syncthreads();
    }
    int run = (t == 0) ? 0 : part[t - 1];
    for (int i = 0; i < chunk; ++i) {
        int idx = base + i;
        if (idx < n) { row_ptr[idx] = run; fill_pos[idx] = run; run += deg[idx]; }
    }
    if (t == 1023) row_ptr[n] = run;   // == E
}

__global__ void fill_kernel(const int* __restrict__ src, const int* __restrict__ dst,
                            int* __restrict__ fill_pos, int* __restrict__ csr, int E) {
    int e = blockIdx.x * blockDim.x + threadIdx.x;
    if (e < E) {
        int d = dst[e];
        int p = atomicAdd(&fill_pos[d], 1);
        csr[p] = src[e];
    }
}

// ---------------- prep ----------------

__global__ void prep_w_kernel(const float* __restrict__ W1l, const float* __restrict__ W1r,
                              const float* __restrict__ W2l, const float* __restrict__ W2r,
                              const float* __restrict__ Wc,
                              __bf16* __restrict__ W1lT, __bf16* __restrict__ W1rT,
                              __bf16* __restrict__ W2lT, __bf16* __restrict__ W2rT,
                              __bf16* __restrict__ WcT) {
    int y = blockIdx.y;
    int k = threadIdx.x;
    if (y < 4) {
        const float* W = (y == 0) ? W1l : (y == 1) ? W1r : (y == 2) ? W2l : W2r;
        __bf16* WT = (y == 0) ? W1lT : (y == 1) ? W1rT : (y == 2) ? W2lT : W2rT;
        int nn = blockIdx.x;
        WT[nn * FEAT + k] = (__bf16)W[k * FEAT + nn];
    } else if (blockIdx.x < NCLS) {
        int c = blockIdx.x;
        WcT[c * FEAT + k] = (__bf16)Wc[k * NCLS + c];
    }
}

// x (f32) -> xb (bf16, GEMM-1 root input) and x8 (fp8 e4m3 gather table)

__global__ void cvt_kernel(const float* __restrict__ x, __bf16* __restrict__ xb,
                           unsigned char* __restrict__ x8, int n4) {
    int i = blockIdx.x * blockDim.x + threadIdx.x;
    if (i < n4) {
        f32x4 v = ((const f32x4*)x)[i];
        bf16x4 o;
        #pragma unroll
        for (int j = 0; j < 4; ++j) o[j] = (__bf16)v[j];
        ((bf16x4*)xb)[i] = o;
        int pk = 0;
        pk = __builtin_amdgcn_cvt_pk_fp8_f32(v[0], v[1], pk, false);
        pk = __builtin_amdgcn_cvt_pk_fp8_f32(v[2], v[3], pk, true);
        ((int*)x8)[i] = pk;
    }
}

// ---------------- mean aggregation, fp8 gather, 4 rows per load instruction ----
// One wave per node. Quad q handles edges beg+q, beg+q+4, ... Each lane loads
// 16 B (16 feats) of its quad's row per iteration; feats per lane = l16*16..+16.
// After the loop, shfl_xor(16/32) butterfly sums quads; lane writes 4 feats
// (offset l16*16 + quad*4) as bf16x4 -> 512 B contiguous per node.

__global__ __launch_bounds__(256) void agg_fp8_kernel(
    const unsigned char* __restrict__ t8, const int* __restrict__ row_ptr,
    const int* __restrict__ csr, __bf16* __restrict__ out, int n)
{
    int wave = threadIdx.x >> 6;
    int node = blockIdx.x * 4 + wave;
    if (node >= n) return;
    int lane = threadIdx.x & 63;
    int quad = lane >> 4, l16 = lane & 15;
    int beg = row_ptr[node], end = row_ptr[node + 1];

    f32x4 s[4];
    #pragma unroll
    for (int w = 0; w < 4; ++w) s[w] = (f32x4){0.f, 0.f, 0.f, 0.f};

    for (int e = beg + quad; e < end; e += 4) {
        int j = csr[e];
        uint4v u = *(const uint4v*)(t8 + (size_t)j * FEAT + l16 * 16);
        #pragma unroll
        for (int w = 0; w < 4; ++w) {
            f32x2 lo = __builtin_amdgcn_cvt_pk_f32_fp8(u[w], false);
            f32x2 hi = __builtin_amdgcn_cvt_pk_f32_fp8(u[w], true);
            s[w][0] += lo[0]; s[w][1] += lo[1]; s[w][2] += hi[0]; s[w][3] += hi[1];
        }
    }

    // butterfly merge across quads
    #pragma unroll
    for (int w = 0; w < 4; ++w)
        #pragma unroll
        for (int j = 0; j < 4; ++j) {
            float v = s[w][j];
            v += __shfl_xor(v, 16, 64);
            v += __shfl_xor(v, 32, 64);
            s[w][j] = v;
        }

    float inv = (end > beg) ? 1.0f / (float)(end - beg) : 0.0f;
    bf16x4 o;
    #pragma unroll
    for (int j = 0; j < 4; ++j) o[j] = (__bf16)(s[quad][j] * inv);
    *(bf16x4*)(out + (size_t)node * FEAT + l16 * 16 + quad * 4) = o;
}

// ---------------- layer-1 GEMM: h = relu(A1@B1 + A2@B2 + b1) -> hb (bf16) + h8 (fp8) ----
// MFMA layouts (HW-verified m89/m91): A: row=lane&15, k=quad*8+j;
// B: col=lane&15, k=quad*8+j; C/D: col=lane&15, row=quad*4+reg.
// Epilogue: tile -> LDS -> vectorized dual-format stores.

__global__ __launch_bounds__(256) void gemm1_kernel(
    const __bf16* __restrict__ A1, const __bf16* __restrict__ A2,
    const __bf16* __restrict__ B1T, const __bf16* __restrict__ B2T,
    const float* __restrict__ bias, __bf16* __restrict__ hb,
    unsigned char* __restrict__ h8, int M)
{
    __shared__ __bf16 ht[32][ZPAD];   // 16.5 KB

    int m0   = blockIdx.x * 32;
    int lane = threadIdx.x & 63;
    int wave = threadIdx.x >> 6;
    int l16  = lane & 15, quad = lane >> 4;

    f32x4 acc[2][4];
    #pragma unroll
    for (int a = 0; a < 2; ++a)
        #pragma unroll
        for (int b = 0; b < 4; ++b) acc[a][b] = (f32x4){0.f, 0.f, 0.f, 0.f};

    int arow[2];
    #pragma unroll
    for (int mt = 0; mt < 2; ++mt) {
        int r = m0 + mt * 16 + l16;
        arow[mt] = (r < M) ? r : (M - 1);
    }
    int nbase = wave * 64;

    for (int pass = 0; pass < 2; ++pass) {
        const __bf16* A  = pass ? A2 : A1;
        const __bf16* BT = pass ? B2T : B1T;
        #pragma unroll 2
        for (int kk = 0; kk < 8; ++kk) {
            int k0 = kk * 32 + quad * 8;
            bf16x8 af[2], bfm[4];
            #pragma unroll
            for (int mt = 0; mt < 2; ++mt)
                af[mt] = *(const bf16x8*)(A + (size_t)arow[mt] * FEAT + k0);
            #pragma unroll
            for (int nt = 0; nt < 4; ++nt)
                bfm[nt] = *(const bf16x8*)(BT + (size_t)(nbase + nt * 16 + l16) * FEAT + k0);
            #pragma unroll
            for (int mt = 0; mt < 2; ++mt)
                #pragma unroll
                for (int nt = 0; nt < 4; ++nt)
                    acc[mt][nt] = __builtin_amdgcn_mfma_f32_16x16x32_bf16(
                        af[mt], bfm[nt], acc[mt][nt], 0, 0, 0);
        }
    }

    // tile (+bias, relu) -> LDS
    #pragma unroll
    for (int nt = 0; nt < 4; ++nt) {
        int col = nbase + nt * 16 + l16;
        float bv = bias[col];
        #pragma unroll
        for (int mt = 0; mt < 2; ++mt) {
            int lr = mt * 16 + quad * 4;
            #pragma unroll
            for (int r = 0; r < 4; ++r) {
                float v = acc[mt][nt][r] + bv;
                v = v > 0.f ? v : 0.f;
                ht[lr + r][col] = (__bf16)v;
            }
        }
    }
    __syncthreads();

    // vector stores: thread -> 32 contiguous feats of one row
    int row = threadIdx.x >> 3;
    int c0  = (threadIdx.x & 7) * 32;
    int grow = m0 + row;
    if (grow < M) {
        #pragma unroll
        for (int i = 0; i < 4; ++i)
            *(bf16x8*)(hb + (size_t)grow * FEAT + c0 + i * 8) = *(const bf16x8*)(&ht[row][c0 + i * 8]);
        unsigned int pk[8];
        #pragma unroll
        for (int i = 0; i < 8; ++i) {
            int b = c0 + i * 4;
            unsigned int w = 0;
            w = __builtin_amdgcn_cvt_pk_fp8_f32((float)ht[row][b],     (float)ht[row][b + 1], w, false);
            w = __builtin_amdgcn_cvt_pk_fp8_f32((float)ht[row][b + 2], (float)ht[row][b + 3], w, true);
            pk[i] = w;
        }
        *(uint4v*)(h8 + (size_t)grow * FEAT + c0)      = *(uint4v*)&pk[0];
        *(uint4v*)(h8 + (size_t)grow * FEAT + c0 + 16) = *(uint4v*)&pk[4];
    }
}

// ---------------- layer-2 GEMM + fused classifier ----------------

__global__ __launch_bounds__(256) void gemm_dual_cls_kernel(
    const __bf16* __restrict__ A1, const __bf16* __restrict__ A2,
    const __bf16* __restrict__ B1T, const __bf16* __restrict__ B2T,
    const float* __restrict__ bias, const __bf16* __restrict__ WcT,
    const float* __restrict__ bc, float* __restrict__ out, int M)
{
    __shared__ __bf16 zt[32 * ZPAD];   // 16.5 KB

    int m0   = blockIdx.x * 32;
    int lane = threadIdx.x & 63;
    int wave = threadIdx.x >> 6;
    int l16  = lane & 15, quad = lane >> 4;

    f32x4 acc[2][4];
    #pragma unroll
    for (int a = 0; a < 2; ++a)
        #pragma unroll
        for (int b = 0; b < 4; ++b) acc[a][b] = (f32x4){0.f, 0.f, 0.f, 0.f};

    int arow[2];
    #pragma unroll
    for (int mt = 0; mt < 2; ++mt) {
        int r = m0 + mt * 16 + l16;
        arow[mt] = (r < M) ? r : (M - 1);
    }
    int nbase = wave * 64;

    for (int pass = 0; pass < 2; ++pass) {
        const __bf16* A  = pass ? A2 : A1;
        const __bf16* BT = pass ? B2T : B1T;
        #pragma unroll 2
        for (int kk = 0; kk < 8; ++kk) {
            int k0 = kk * 32 + quad * 8;
            bf16x8 af[2], bfm[4];
            #pragma unroll
            for (int mt = 0; mt < 2; ++mt)
                af[mt] = *(const bf16x8*)(A + (size_t)arow[mt] * FEAT + k0);
            #pragma unroll
            for (int nt = 0; nt < 4; ++nt)
                bfm[nt] = *(const bf16x8*)(BT + (size_t)(nbase + nt * 16 + l16) * FEAT + k0);
            #pragma unroll
            for (int mt = 0; mt < 2; ++mt)
                #pragma unroll
                for (int nt = 0; nt < 4; ++nt)
                    acc[mt][nt] = __builtin_amdgcn_mfma_f32_16x16x32_bf16(
                        af[mt], bfm[nt], acc[mt][nt], 0, 0, 0);
        }
    }

    // epilogue: z (+b2) -> LDS
    #pragma unroll
    for (int nt = 0; nt < 4; ++nt) {
        int col = nbase + nt * 16 + l16;
        float bv = bias[col];
        #pragma unroll
        for (int mt = 0; mt < 2; ++mt) {
            int lr = mt * 16 + quad * 4;
            #pragma unroll
            for (int r = 0; r < 4; ++r)
                zt[(lr + r) * ZPAD + col] = (__bf16)(acc[mt][nt][r] + bv);
        }
    }
    __syncthreads();

    // classifier: waves 0/1, 16 rows each; B-frag from WcT (L2-hot)
    if (wave < 2) {
        int lr = wave * 16 + l16;
        f32x4 c = {0.f, 0.f, 0.f, 0.f};
        #pragma unroll
        for (int kk = 0; kk < 8; ++kk) {
            int k0 = kk * 32 + quad * 8;
            bf16x8 a = *(const bf16x8*)(&zt[lr * ZPAD + k0]);
            bf16x8 b = *(const bf16x8*)(WcT + (size_t)l16 * FEAT + k0);
            c = __builtin_amdgcn_mfma_f32_16x16x32_bf16(a, b, c, 0, 0, 0);
        }
        float bv = bc[l16];
        #pragma unroll
        for (int r = 0; r < 4; ++r) {
            int row = m0 + wave * 16 + quad * 4 + r;
            if (row < M) out[(size_t)row * NCLS + l16] = c[r] + bv;
        }
    }
}

// ---------------- launch ----------------

extern "C" void kernel_launch(void* const* d_in, const int* in_sizes, int n_in,
                              void* d_out, int out_size, void* d_ws, size_t ws_size,
                              hipStream_t stream) {
    const float* x   = (const float*)d_in[0];
    const int*   ei  = (const int*)d_in[1];
    const float* W1l = (const float*)d_in[2];
    const float* b1  = (const float*)d_in[3];
    const float* W1r = (const float*)d_in[4];
    const float* W2l = (const float*)d_in[5];
    const float* b2  = (const float*)d_in[6];
    const float* W2r = (const float*)d_in[7];
    const float* Wc  = (const float*)d_in[8];
    const float* bc  = (const float*)d_in[9];
    float* out = (float*)d_out;

    const int n = in_sizes[0] / FEAT;   // 20000
    const int E = in_sizes[1] / 2;      // 640000
    const int* srcp = ei;
    const int* dstp = ei + E;

    char* p = (char*)d_ws;
    auto alloc = [&](size_t bytes) { char* r = p; p += (bytes + 511) & ~511ull; return r; };
    int* deg       = (int*)alloc((size_t)n * 4);
    int* row_ptr   = (int*)alloc((size_t)(n + 1) * 4);
    int* fill_pos  = (int*)alloc((size_t)n * 4);
    int* csr       = (int*)alloc((size_t)E * 4);
    __bf16* W1lT   = (__bf16*)alloc((size_t)FEAT * FEAT * 2);
    __bf16* W1rT   = (__bf16*)alloc((size_t)FEAT * FEAT * 2);
    __bf16* W2lT   = (__bf16*)alloc((size_t)FEAT * FEAT * 2);
    __bf16* W2rT   = (__bf16*)alloc((size_t)FEAT * FEAT * 2);
    __bf16* WcT    = (__bf16*)alloc((size_t)NCLS * FEAT * 2);
    __bf16* xb     = (__bf16*)alloc((size_t)n * FEAT * 2);
    unsigned char* x8 = (unsigned char*)alloc((size_t)n * FEAT);
    unsigned char* h8 = (unsigned char*)alloc((size_t)n * FEAT);
    __bf16* aggb   = (__bf16*)alloc((size_t)n * FEAT * 2);
    __bf16* hb     = (__bf16*)alloc((size_t)n * FEAT * 2);

    // CSR build
    hipMemsetAsync(deg, 0, (size_t)n * 4, stream);
    count_deg_kernel<<<(E + 255) / 256, 256, 0, stream>>>(dstp, deg, E);
    scan_kernel<<<1, 1024, 0, stream>>>(deg, row_ptr, fill_pos, n);
    fill_kernel<<<(E + 255) / 256, 256, 0, stream>>>(srcp, dstp, fill_pos, csr, E);

    // prep
    prep_w_kernel<<<dim3(FEAT, 5), FEAT, 0, stream>>>(W1l, W1r, W2l, W2r, Wc,
                                                      W1lT, W1rT, W2lT, W2rT, WcT);
    int n4 = n * FEAT / 4;
    cvt_kernel<<<(n4 + 255) / 256, 256, 0, stream>>>(x, xb, x8, n4);

    // layer 1
    agg_fp8_kernel<<<(n + 3) / 4, 256, 0, stream>>>(x8, row_ptr, csr, aggb, n);
    gemm1_kernel<<<(n + 31) / 32, 256, 0, stream>>>(aggb, xb, W1lT, W1rT, b1, hb, h8, n);

    // layer 2 + fused classifier
    agg_fp8_kernel<<<(n + 3) / 4, 256, 0, stream>>>(h8, row_ptr, csr, aggb, n);
    gemm_dual_cls_kernel<<<(n + 31) / 32, 256, 0, stream>>>(aggb, hb, W2lT, W2rT, b2,
                                                            WcT, bc, out, n);
}